// Round 18
// baseline (103.685 us; speedup 1.0000x reference)
//
#include <hip/hip_runtime.h>
#include <hip/hip_bf16.h>

#define DD 128
#define DEG 32

typedef __attribute__((ext_vector_type(8))) _Float16 half8;
typedef __attribute__((ext_vector_type(4))) float f32x4;

__device__ __forceinline__ unsigned pkh(float a, float b) {
    _Float16 ha = (_Float16)a, hb = (_Float16)b;     // RNE v_cvt_f16_f32
    return (unsigned)__builtin_bit_cast(unsigned short, ha)
         | ((unsigned)__builtin_bit_cast(unsigned short, hb) << 16);
}
__device__ __forceinline__ float h2f_lo(unsigned u) {
    return (float)__builtin_bit_cast(_Float16, (unsigned short)(u & 0xffff));
}
__device__ __forceinline__ float h2f_hi(unsigned u) {
    return (float)__builtin_bit_cast(_Float16, (unsigned short)(u >> 16));
}

// ---------------------------------------------------------------------------
// k_aux: fused prep (blocks 0..23) + cast (remaining blocks).
//  w1img[(nt*4+k4)*64+l][i] = B1[k4*32+(l>>4)*8+i][nt*16+(l&15)]  (fp16)
//     B1[k][n] = W1[k][n] (n<128 -> "W1a") | W1[128+k][n-128] (n>=128 -> "W1b")
//  w2t  [(mt*4+k4)*64+l][i] = W2[k4*32+(l>>4)*8+i][mt*16+(l&15)]  (fp16)
//  ub16 = fp16(u2e), streaming cast.
// ---------------------------------------------------------------------------
__global__ __launch_bounds__(256) void k_aux(
    const float* __restrict__ W1, const float* __restrict__ W2,
    const float4* __restrict__ u2e4, uint4* __restrict__ w1img,
    uint4* __restrict__ w2t, uint4* __restrict__ ub16v, int total8)
{
    const int bid = blockIdx.x;
    if (bid < 24) {
        int t = bid * 256 + threadIdx.x;
        if (t < 4096) {
            int l = t & 63, f = t >> 6, k4 = f & 3, nt = f >> 2;
            int n = nt * 16 + (l & 15), kb = k4 * 32 + ((l >> 4) & 3) * 8;
            float v[8];
            #pragma unroll
            for (int i = 0; i < 8; ++i) {
                int k = kb + i;
                v[i] = (n < DD) ? W1[k * DD + n] : W1[(DD + k) * DD + (n - DD)];
            }
            uint4 r;
            r.x = pkh(v[0], v[1]); r.y = pkh(v[2], v[3]);
            r.z = pkh(v[4], v[5]); r.w = pkh(v[6], v[7]);
            w1img[t] = r;
        } else if (t < 6144) {
            int q = t - 4096;
            int l = q & 63, f = q >> 6, k4 = f & 3, mt = f >> 2;
            int ch = mt * 16 + (l & 15), kb = k4 * 32 + ((l >> 4) & 3) * 8;
            float v[8];
            #pragma unroll
            for (int i = 0; i < 8; ++i) v[i] = W2[(kb + i) * DD + ch];
            uint4 r;
            r.x = pkh(v[0], v[1]); r.y = pkh(v[2], v[3]);
            r.z = pkh(v[4], v[5]); r.w = pkh(v[6], v[7]);
            w2t[q] = r;
        }
    } else {
        int i = (bid - 24) * 256 + threadIdx.x;
        if (i < total8) {
            float4 v0 = u2e4[(size_t)i * 2], v1 = u2e4[(size_t)i * 2 + 1];
            uint4 r;
            r.x = pkh(v0.x, v0.y); r.y = pkh(v0.z, v0.w);
            r.z = pkh(v1.x, v1.y); r.w = pkh(v1.z, v1.w);
            ub16v[i] = r;
        }
    }
}

// ---------------------------------------------------------------------------
// k_qn: Qnh[i] = fp16(u2e[nodes[i]] @ W1b + b1) — only the 20k centers.
// Per-lane gathered fp32->fp16 A-fragments, B=w1b image (w1img nt 8..15).
// ---------------------------------------------------------------------------
__global__ __launch_bounds__(256) void k_qn(
    const int* __restrict__ nodes, const float* __restrict__ u2e,
    const uint4* __restrict__ w1img, const float* __restrict__ b1,
    unsigned short* __restrict__ Qnh, int n)
{
    const int t = threadIdx.x, w = t >> 6, l = t & 63;
    const int base = blockIdx.x * 128;

    half8 a[2][4];
    #pragma unroll
    for (int nt = 0; nt < 2; ++nt) {
        int row = min(base + w * 32 + nt * 16 + (l & 15), n - 1);
        int user = nodes[row];
        const float* rp = u2e + (size_t)user * DD + ((l >> 4) << 3);
        #pragma unroll
        for (int k4 = 0; k4 < 4; ++k4) {
            float4 v0 = *reinterpret_cast<const float4*>(rp + k4 * 32);
            float4 v1 = *reinterpret_cast<const float4*>(rp + k4 * 32 + 4);
            uint4 r;
            r.x = pkh(v0.x, v0.y); r.y = pkh(v0.z, v0.w);
            r.z = pkh(v1.x, v1.y); r.w = pkh(v1.z, v1.w);
            a[nt][k4] = __builtin_bit_cast(half8, r);
        }
    }
    const int chq = (l >> 4) << 2;
    #pragma unroll
    for (int mt = 0; mt < 8; ++mt) {
        half8 wf[4];
        #pragma unroll
        for (int k4 = 0; k4 < 4; ++k4)
            wf[k4] = __builtin_bit_cast(half8, w1img[((8 + mt) * 4 + k4) * 64 + l]);
        float4 b1v = *reinterpret_cast<const float4*>(&b1[mt * 16 + chq]);
        #pragma unroll
        for (int nt = 0; nt < 2; ++nt) {
            f32x4 acc = {0.f, 0.f, 0.f, 0.f};
            #pragma unroll
            for (int k4 = 0; k4 < 4; ++k4)
                acc = __builtin_amdgcn_mfma_f32_16x16x32_f16(wf[k4], a[nt][k4], acc, 0, 0, 0);
            int row = base + w * 32 + nt * 16 + (l & 15);
            if (row < n) {
                uint2 pk;
                pk.x = pkh(acc[0] + b1v.x, acc[1] + b1v.y);
                pk.y = pkh(acc[2] + b1v.z, acc[3] + b1v.w);
                *reinterpret_cast<uint2*>(&Qnh[(size_t)row * DD + mt * 16 + chq]) = pk;
            }
        }
    }
}

// ---------------------------------------------------------------------------
// k_node: PERSISTENT — 512 blocks x 512 thr, 1 node/wave/iter, 5 nodes/wave.
// Round-17 structure (82.4us, no spill) + two prefetches that close the
// remaining exposed load chains:
//  1. qnh ping-pong: next node's Qnh row (8x uint2) loads issue in the
//     post-softmax slot; GEMM1 reads registers (was: 8 serialized L2/L3
//     loads inside GEMM1, ~300cy each partially exposed).
//  2. next-node neigh indices loaded at iteration TOP, so the post-softmax
//     ub gathers issue without waiting on the index load.
// Register phases (all <128, unified VGPR+AGPR): GEMM2 ~100, tail ~96.
// sched_barrier(0) pins the post-softmax load block (r14 spill lesson).
// ---------------------------------------------------------------------------
__global__ __launch_bounds__(512, 4) void k_node(
    const int* __restrict__ neigh, const _Float16* __restrict__ ub16,
    const unsigned short* __restrict__ Qnh, const uint4* __restrict__ w1img,
    const uint4* __restrict__ w2t, const float* __restrict__ b2,
    const float* __restrict__ w3, float4* __restrict__ out4, int n)
{
    __shared__ uint4 s_img[4096];     // [0..2047]=w1a frags, [2048..4095]=w2t

    const int t = threadIdx.x, w = t >> 6, l = t & 63;
    const int g = l >> 4, c = l & 15;
    const int koff = g * 8;
    const int base = blockIdx.x * 40 + w * 5;   // this wave's 5 nodes

    // ---- prologue: issue it=0 gathers + qnh before staging (overlap)
    half8 ub0[2][4], ub1[2][4];
    uint2 qnh[2][8];
    {
        int node0 = min(base, n - 1);
        int i0 = neigh[node0 * DEG + c];
        int i1 = neigh[node0 * DEG + 16 + c];
        #pragma unroll
        for (int k4 = 0; k4 < 4; ++k4)
            ub0[0][k4] = *reinterpret_cast<const half8*>(
                &ub16[(size_t)i0 * DD + k4 * 32 + koff]);
        #pragma unroll
        for (int k4 = 0; k4 < 4; ++k4)
            ub1[0][k4] = *reinterpret_cast<const half8*>(
                &ub16[(size_t)i1 * DD + k4 * 32 + koff]);
        #pragma unroll
        for (int mt = 0; mt < 8; ++mt)
            qnh[0][mt] = *reinterpret_cast<const uint2*>(
                &Qnh[(size_t)node0 * DD + mt * 16 + g * 4]);
    }

    // ---- stage weight images once
    #pragma unroll
    for (int i = 0; i < 4; ++i) s_img[i * 512 + t] = w1img[i * 512 + t];
    #pragma unroll
    for (int i = 0; i < 4; ++i) s_img[2048 + i * 512 + t] = w2t[i * 512 + t];
    __syncthreads();

    const int srcA = ((g & 1) << 5) + c;
    const int hiSel = g >> 1;

    #pragma unroll
    for (int it = 0; it < 5; ++it) {
        const int cur = it & 1, nxt = cur ^ 1;
        const int node = min(base + it, n - 1);

        // ---- prefetch NEXT node's neigh indices (heads the gather chain)
        int j0 = 0, j1 = 0, nn = 0;
        if (it < 4) {
            nn = min(base + it + 1, n - 1);
            j0 = neigh[nn * DEG + c];
            j1 = neigh[nn * DEG + 16 + c];
        }

        // ---- fused GEMM1 + epilogue + relayout, one k4 (2 ch-tiles) at a time
        half8 hb0[4], hb1[4];
        #pragma unroll
        for (int k4 = 0; k4 < 4; ++k4) {
            uint2 hpA0, hpA1, hpB0, hpB1;   // hp{edge-half}{mt-parity}
            {   // mt = 2k4
                const int mt = 2 * k4;
                uint2 qn = qnh[cur][mt];
                half8 wf[4];
                #pragma unroll
                for (int kk = 0; kk < 4; ++kk)
                    wf[kk] = __builtin_bit_cast(half8, s_img[(mt * 4 + kk) * 64 + l]);
                f32x4 a0 = {0.f, 0.f, 0.f, 0.f}, a1 = {0.f, 0.f, 0.f, 0.f};
                #pragma unroll
                for (int kk = 0; kk < 4; ++kk)
                    a0 = __builtin_amdgcn_mfma_f32_16x16x32_f16(wf[kk], ub0[cur][kk], a0, 0, 0, 0);
                #pragma unroll
                for (int kk = 0; kk < 4; ++kk)
                    a1 = __builtin_amdgcn_mfma_f32_16x16x32_f16(wf[kk], ub1[cur][kk], a1, 0, 0, 0);
                float q0 = h2f_lo(qn.x), q1 = h2f_hi(qn.x);
                float q2 = h2f_lo(qn.y), q3 = h2f_hi(qn.y);
                hpA0.x = pkh(fmaxf(a0[0] + q0, 0.f), fmaxf(a0[1] + q1, 0.f));
                hpA0.y = pkh(fmaxf(a0[2] + q2, 0.f), fmaxf(a0[3] + q3, 0.f));
                hpB0.x = pkh(fmaxf(a1[0] + q0, 0.f), fmaxf(a1[1] + q1, 0.f));
                hpB0.y = pkh(fmaxf(a1[2] + q2, 0.f), fmaxf(a1[3] + q3, 0.f));
            }
            {   // mt = 2k4 + 1
                const int mt = 2 * k4 + 1;
                uint2 qn = qnh[cur][mt];
                half8 wf[4];
                #pragma unroll
                for (int kk = 0; kk < 4; ++kk)
                    wf[kk] = __builtin_bit_cast(half8, s_img[(mt * 4 + kk) * 64 + l]);
                f32x4 a0 = {0.f, 0.f, 0.f, 0.f}, a1 = {0.f, 0.f, 0.f, 0.f};
                #pragma unroll
                for (int kk = 0; kk < 4; ++kk)
                    a0 = __builtin_amdgcn_mfma_f32_16x16x32_f16(wf[kk], ub0[cur][kk], a0, 0, 0, 0);
                #pragma unroll
                for (int kk = 0; kk < 4; ++kk)
                    a1 = __builtin_amdgcn_mfma_f32_16x16x32_f16(wf[kk], ub1[cur][kk], a1, 0, 0, 0);
                float q0 = h2f_lo(qn.x), q1 = h2f_hi(qn.x);
                float q2 = h2f_lo(qn.y), q3 = h2f_hi(qn.y);
                hpA1.x = pkh(fmaxf(a0[0] + q0, 0.f), fmaxf(a0[1] + q1, 0.f));
                hpA1.y = pkh(fmaxf(a0[2] + q2, 0.f), fmaxf(a0[3] + q3, 0.f));
                hpB1.x = pkh(fmaxf(a1[0] + q0, 0.f), fmaxf(a1[1] + q1, 0.f));
                hpB1.y = pkh(fmaxf(a1[2] + q2, 0.f), fmaxf(a1[3] + q3, 0.f));
            }
            // relayout this k4; hp regs die here
            unsigned d[4], e[4];
            #pragma unroll
            for (int j = 0; j < 4; ++j) {
                int src = srcA + ((j >> 1) << 4);
                unsigned vE = (unsigned)__shfl((int)((j & 1) ? hpA0.y : hpA0.x), src);
                unsigned vO = (unsigned)__shfl((int)((j & 1) ? hpA1.y : hpA1.x), src);
                d[j] = hiSel ? vO : vE;
                unsigned uE = (unsigned)__shfl((int)((j & 1) ? hpB0.y : hpB0.x), src);
                unsigned uO = (unsigned)__shfl((int)((j & 1) ? hpB1.y : hpB1.x), src);
                e[j] = hiSel ? uO : uE;
            }
            uint4 du = {d[0], d[1], d[2], d[3]};
            uint4 eu = {e[0], e[1], e[2], e[3]};
            hb0[k4] = __builtin_bit_cast(half8, du);
            hb1[k4] = __builtin_bit_cast(half8, eu);
        }

        // ---- GEMM2 + logit fold (setprio: independent waves, attn-like)
        __builtin_amdgcn_s_setprio(1);
        float pl0 = 0.f, pl1 = 0.f;
        #pragma unroll
        for (int mt = 0; mt < 8; ++mt) {
            half8 wf[4];
            #pragma unroll
            for (int k4 = 0; k4 < 4; ++k4)
                wf[k4] = __builtin_bit_cast(half8, s_img[2048 + (mt * 4 + k4) * 64 + l]);
            float4 b2v = *reinterpret_cast<const float4*>(&b2[mt * 16 + g * 4]);
            float4 w3v = *reinterpret_cast<const float4*>(&w3[mt * 16 + g * 4]);
            f32x4 a0 = {0.f, 0.f, 0.f, 0.f}, a1 = {0.f, 0.f, 0.f, 0.f};
            #pragma unroll
            for (int k4 = 0; k4 < 4; ++k4)
                a0 = __builtin_amdgcn_mfma_f32_16x16x32_f16(wf[k4], hb0[k4], a0, 0, 0, 0);
            #pragma unroll
            for (int k4 = 0; k4 < 4; ++k4)
                a1 = __builtin_amdgcn_mfma_f32_16x16x32_f16(wf[k4], hb1[k4], a1, 0, 0, 0);
            pl0 += fmaxf(a0[0] + b2v.x, 0.f) * w3v.x + fmaxf(a0[1] + b2v.y, 0.f) * w3v.y
                 + fmaxf(a0[2] + b2v.z, 0.f) * w3v.z + fmaxf(a0[3] + b2v.w, 0.f) * w3v.w;
            pl1 += fmaxf(a1[0] + b2v.x, 0.f) * w3v.x + fmaxf(a1[1] + b2v.y, 0.f) * w3v.y
                 + fmaxf(a1[2] + b2v.z, 0.f) * w3v.z + fmaxf(a1[3] + b2v.w, 0.f) * w3v.w;
        }
        __builtin_amdgcn_s_setprio(0);
        pl0 += __shfl_xor(pl0, 16); pl0 += __shfl_xor(pl0, 32);
        pl1 += __shfl_xor(pl1, 16); pl1 += __shfl_xor(pl1, 32);

        // ---- in-wave softmax over the 32 edges
        float mx = fmaxf(pl0, pl1);
        #pragma unroll
        for (int mask = 1; mask <= 8; mask <<= 1) mx = fmaxf(mx, __shfl_xor(mx, mask));
        float e0 = __expf(pl0 - mx), e1 = __expf(pl1 - mx);
        float sm = e0 + e1;
        #pragma unroll
        for (int mask = 1; mask <= 8; mask <<= 1) sm += __shfl_xor(sm, mask);
        float inv = __frcp_rn(sm);
        float att0 = e0 * inv, att1 = e1 * inv;  // att for edges c and 16+c

        // ---- NOW issue next node's gathers + qnh (hb dead -> regs free).
        // sched_barrier(0) pins placement (must not hoist into GEMM2).
        __builtin_amdgcn_sched_barrier(0);
        if (it < 4) {
            #pragma unroll
            for (int k4 = 0; k4 < 4; ++k4)
                ub0[nxt][k4] = *reinterpret_cast<const half8*>(
                    &ub16[(size_t)j0 * DD + k4 * 32 + koff]);
            #pragma unroll
            for (int k4 = 0; k4 < 4; ++k4)
                ub1[nxt][k4] = *reinterpret_cast<const half8*>(
                    &ub16[(size_t)j1 * DD + k4 * 32 + koff]);
            #pragma unroll
            for (int mt = 0; mt < 8; ++mt)
                qnh[nxt][mt] = *reinterpret_cast<const uint2*>(
                    &Qnh[(size_t)nn * DD + mt * 16 + g * 4]);
        }

        // ---- weighted sum, ONE k4 at a time (8 live regs)
        #pragma unroll
        for (int k4 = 0; k4 < 4; ++k4) {
            float o8[8];
            #pragma unroll
            for (int i = 0; i < 8; ++i)
                o8[i] = att0 * (float)ub0[cur][k4][i] + att1 * (float)ub1[cur][k4][i];
            #pragma unroll
            for (int mask = 1; mask <= 8; mask <<= 1) {
                #pragma unroll
                for (int i = 0; i < 8; ++i)
                    o8[i] += __shfl_xor(o8[i], mask);
            }
            if (c == 0) {   // lanes (g,0): store ch = 32*k4 + 8*g + {0..7}
                float4 r0 = make_float4(o8[0], o8[1], o8[2], o8[3]);
                float4 r1 = make_float4(o8[4], o8[5], o8[6], o8[7]);
                out4[(size_t)node * 32 + k4 * 8 + g * 2]     = r0;
                out4[(size_t)node * 32 + k4 * 8 + g * 2 + 1] = r1;
            }
        }
    }
}

// ---------------------------------------------------------------------------
extern "C" void kernel_launch(void* const* d_in, const int* in_sizes, int n_in,
                              void* d_out, int out_size, void* d_ws, size_t ws_size,
                              hipStream_t stream)
{
    const int*   nodes = (const int*)  d_in[0];
    const int*   neigh = (const int*)  d_in[1];
    const float* u2e   = (const float*)d_in[3];
    const float* W1    = (const float*)d_in[4];
    const float* b1    = (const float*)d_in[5];
    const float* W2    = (const float*)d_in[6];
    const float* b2    = (const float*)d_in[7];
    const float* w3    = (const float*)d_in[8];
    // d_in[9] b3: cancels in segment softmax

    const int n = in_sizes[0];            // 20000
    const int U = in_sizes[3] / DD;       // 100000

    uint4*          w1img = (uint4*)d_ws;                    // 64 KB
    uint4*          w2t   = w1img + 4096;                    // 32 KB
    _Float16*       ub16  = (_Float16*)(w2t + 2048);         // 25.6 MB
    unsigned short* Qnh   = (unsigned short*)(ub16 + (size_t)U * DD); // 5.12 MB

    const int total8 = U * (DD / 8);      // 1.6M half8 chunks

    k_aux<<<24 + (total8 + 255) / 256, 256, 0, stream>>>(
        W1, W2, (const float4*)u2e, w1img, w2t, (uint4*)ub16, total8);
    k_qn<<<(n + 127) / 128, 256, 0, stream>>>(nodes, u2e, w1img, b1, Qnh, n);
    k_node<<<512, 512, 0, stream>>>(neigh, ub16, Qnh, w1img, w2t,
                                    b2, w3, (float4*)d_out, n);
}

// Round 19
// 100.770 us; speedup vs baseline: 1.0289x; 1.0289x over previous
//
#include <hip/hip_runtime.h>
#include <hip/hip_bf16.h>

#define DD 128
#define DEG 32

typedef __attribute__((ext_vector_type(8))) _Float16 half8;
typedef __attribute__((ext_vector_type(4))) float f32x4;

__device__ __forceinline__ unsigned pkh(float a, float b) {
    _Float16 ha = (_Float16)a, hb = (_Float16)b;     // RNE v_cvt_f16_f32
    return (unsigned)__builtin_bit_cast(unsigned short, ha)
         | ((unsigned)__builtin_bit_cast(unsigned short, hb) << 16);
}
__device__ __forceinline__ float h2f_lo(unsigned u) {
    return (float)__builtin_bit_cast(_Float16, (unsigned short)(u & 0xffff));
}
__device__ __forceinline__ float h2f_hi(unsigned u) {
    return (float)__builtin_bit_cast(_Float16, (unsigned short)(u >> 16));
}

// ---------------------------------------------------------------------------
// k_aux: fused prep (blocks 0..23) + cast (remaining blocks).
//  w1img[(nt*4+k4)*64+l][i] = B1[k4*32+(l>>4)*8+i][nt*16+(l&15)]  (fp16)
//     B1[k][n] = W1[k][n] (n<128 -> "W1a") | W1[128+k][n-128] (n>=128 -> "W1b")
//  w2t  [(mt*4+k4)*64+l][i] = W2[k4*32+(l>>4)*8+i][mt*16+(l&15)]  (fp16)
//  ub16 = fp16(u2e), streaming cast.
// ---------------------------------------------------------------------------
__global__ __launch_bounds__(256) void k_aux(
    const float* __restrict__ W1, const float* __restrict__ W2,
    const float4* __restrict__ u2e4, uint4* __restrict__ w1img,
    uint4* __restrict__ w2t, uint4* __restrict__ ub16v, int total8)
{
    const int bid = blockIdx.x;
    if (bid < 24) {
        int t = bid * 256 + threadIdx.x;
        if (t < 4096) {
            int l = t & 63, f = t >> 6, k4 = f & 3, nt = f >> 2;
            int n = nt * 16 + (l & 15), kb = k4 * 32 + ((l >> 4) & 3) * 8;
            float v[8];
            #pragma unroll
            for (int i = 0; i < 8; ++i) {
                int k = kb + i;
                v[i] = (n < DD) ? W1[k * DD + n] : W1[(DD + k) * DD + (n - DD)];
            }
            uint4 r;
            r.x = pkh(v[0], v[1]); r.y = pkh(v[2], v[3]);
            r.z = pkh(v[4], v[5]); r.w = pkh(v[6], v[7]);
            w1img[t] = r;
        } else if (t < 6144) {
            int q = t - 4096;
            int l = q & 63, f = q >> 6, k4 = f & 3, mt = f >> 2;
            int ch = mt * 16 + (l & 15), kb = k4 * 32 + ((l >> 4) & 3) * 8;
            float v[8];
            #pragma unroll
            for (int i = 0; i < 8; ++i) v[i] = W2[(kb + i) * DD + ch];
            uint4 r;
            r.x = pkh(v[0], v[1]); r.y = pkh(v[2], v[3]);
            r.z = pkh(v[4], v[5]); r.w = pkh(v[6], v[7]);
            w2t[q] = r;
        }
    } else {
        int i = (bid - 24) * 256 + threadIdx.x;
        if (i < total8) {
            float4 v0 = u2e4[(size_t)i * 2], v1 = u2e4[(size_t)i * 2 + 1];
            uint4 r;
            r.x = pkh(v0.x, v0.y); r.y = pkh(v0.z, v0.w);
            r.z = pkh(v1.x, v1.y); r.w = pkh(v1.z, v1.w);
            ub16v[i] = r;
        }
    }
}

// ---------------------------------------------------------------------------
// k_qn: Qnh[i] = fp16(u2e[nodes[i]] @ W1b + b1) — only the 20k centers.
// Per-lane gathered fp32->fp16 A-fragments, B=w1b image (w1img nt 8..15).
// ---------------------------------------------------------------------------
__global__ __launch_bounds__(256) void k_qn(
    const int* __restrict__ nodes, const float* __restrict__ u2e,
    const uint4* __restrict__ w1img, const float* __restrict__ b1,
    unsigned short* __restrict__ Qnh, int n)
{
    const int t = threadIdx.x, w = t >> 6, l = t & 63;
    const int base = blockIdx.x * 128;

    half8 a[2][4];
    #pragma unroll
    for (int nt = 0; nt < 2; ++nt) {
        int row = min(base + w * 32 + nt * 16 + (l & 15), n - 1);
        int user = nodes[row];
        const float* rp = u2e + (size_t)user * DD + ((l >> 4) << 3);
        #pragma unroll
        for (int k4 = 0; k4 < 4; ++k4) {
            float4 v0 = *reinterpret_cast<const float4*>(rp + k4 * 32);
            float4 v1 = *reinterpret_cast<const float4*>(rp + k4 * 32 + 4);
            uint4 r;
            r.x = pkh(v0.x, v0.y); r.y = pkh(v0.z, v0.w);
            r.z = pkh(v1.x, v1.y); r.w = pkh(v1.z, v1.w);
            a[nt][k4] = __builtin_bit_cast(half8, r);
        }
    }
    const int chq = (l >> 4) << 2;
    #pragma unroll
    for (int mt = 0; mt < 8; ++mt) {
        half8 wf[4];
        #pragma unroll
        for (int k4 = 0; k4 < 4; ++k4)
            wf[k4] = __builtin_bit_cast(half8, w1img[((8 + mt) * 4 + k4) * 64 + l]);
        float4 b1v = *reinterpret_cast<const float4*>(&b1[mt * 16 + chq]);
        #pragma unroll
        for (int nt = 0; nt < 2; ++nt) {
            f32x4 acc = {0.f, 0.f, 0.f, 0.f};
            #pragma unroll
            for (int k4 = 0; k4 < 4; ++k4)
                acc = __builtin_amdgcn_mfma_f32_16x16x32_f16(wf[k4], a[nt][k4], acc, 0, 0, 0);
            int row = base + w * 32 + nt * 16 + (l & 15);
            if (row < n) {
                uint2 pk;
                pk.x = pkh(acc[0] + b1v.x, acc[1] + b1v.y);
                pk.y = pkh(acc[2] + b1v.z, acc[3] + b1v.w);
                *reinterpret_cast<uint2*>(&Qnh[(size_t)row * DD + mt * 16 + chq]) = pk;
            }
        }
    }
}

// ---------------------------------------------------------------------------
// k_node: PERSISTENT — 512 blocks x 512 thr, 1 node/wave/iter, 5 nodes/wave.
// Round-17 structure (82.4us, no spill) + next-node INDEX prefetch only.
// (Round 18's qnh[2][8] ping-pong added 16 live regs -> 6MB scratch spill,
// 86.9us — reverted. Qnh loads stay inside GEMM1 where epilogue work covers
// them.) Indices j0/j1 load at iteration TOP so the post-softmax ub gathers
// issue without the ~300cy index-load dependency.
// sched_barrier(0) pins the post-softmax gather block (r14 spill lesson).
// ---------------------------------------------------------------------------
__global__ __launch_bounds__(512, 4) void k_node(
    const int* __restrict__ neigh, const _Float16* __restrict__ ub16,
    const unsigned short* __restrict__ Qnh, const uint4* __restrict__ w1img,
    const uint4* __restrict__ w2t, const float* __restrict__ b2,
    const float* __restrict__ w3, float4* __restrict__ out4, int n)
{
    __shared__ uint4 s_img[4096];     // [0..2047]=w1a frags, [2048..4095]=w2t

    const int t = threadIdx.x, w = t >> 6, l = t & 63;
    const int g = l >> 4, c = l & 15;
    const int koff = g * 8;
    const int base = blockIdx.x * 40 + w * 5;   // this wave's 5 nodes

    // ---- prologue: issue it=0 gathers before staging (overlap)
    half8 ub0[2][4], ub1[2][4];
    {
        int node0 = min(base, n - 1);
        int i0 = neigh[node0 * DEG + c];
        int i1 = neigh[node0 * DEG + 16 + c];
        #pragma unroll
        for (int k4 = 0; k4 < 4; ++k4)
            ub0[0][k4] = *reinterpret_cast<const half8*>(
                &ub16[(size_t)i0 * DD + k4 * 32 + koff]);
        #pragma unroll
        for (int k4 = 0; k4 < 4; ++k4)
            ub1[0][k4] = *reinterpret_cast<const half8*>(
                &ub16[(size_t)i1 * DD + k4 * 32 + koff]);
    }

    // ---- stage weight images once
    #pragma unroll
    for (int i = 0; i < 4; ++i) s_img[i * 512 + t] = w1img[i * 512 + t];
    #pragma unroll
    for (int i = 0; i < 4; ++i) s_img[2048 + i * 512 + t] = w2t[i * 512 + t];
    __syncthreads();

    const int srcA = ((g & 1) << 5) + c;
    const int hiSel = g >> 1;

    #pragma unroll
    for (int it = 0; it < 5; ++it) {
        const int cur = it & 1, nxt = cur ^ 1;
        const int node = min(base + it, n - 1);

        // ---- prefetch NEXT node's neigh indices (heads the gather chain)
        int j0 = 0, j1 = 0;
        if (it < 4) {
            int nn = min(base + it + 1, n - 1);
            j0 = neigh[nn * DEG + c];
            j1 = neigh[nn * DEG + 16 + c];
        }

        // ---- fused GEMM1 + epilogue + relayout, one k4 (2 ch-tiles) at a time
        half8 hb0[4], hb1[4];
        #pragma unroll
        for (int k4 = 0; k4 < 4; ++k4) {
            uint2 hpA0, hpA1, hpB0, hpB1;   // hp{edge-half}{mt-parity}
            {   // mt = 2k4
                const int mt = 2 * k4;
                uint2 qn = *reinterpret_cast<const uint2*>(
                    &Qnh[(size_t)node * DD + mt * 16 + g * 4]);
                half8 wf[4];
                #pragma unroll
                for (int kk = 0; kk < 4; ++kk)
                    wf[kk] = __builtin_bit_cast(half8, s_img[(mt * 4 + kk) * 64 + l]);
                f32x4 a0 = {0.f, 0.f, 0.f, 0.f}, a1 = {0.f, 0.f, 0.f, 0.f};
                #pragma unroll
                for (int kk = 0; kk < 4; ++kk)
                    a0 = __builtin_amdgcn_mfma_f32_16x16x32_f16(wf[kk], ub0[cur][kk], a0, 0, 0, 0);
                #pragma unroll
                for (int kk = 0; kk < 4; ++kk)
                    a1 = __builtin_amdgcn_mfma_f32_16x16x32_f16(wf[kk], ub1[cur][kk], a1, 0, 0, 0);
                float q0 = h2f_lo(qn.x), q1 = h2f_hi(qn.x);
                float q2 = h2f_lo(qn.y), q3 = h2f_hi(qn.y);
                hpA0.x = pkh(fmaxf(a0[0] + q0, 0.f), fmaxf(a0[1] + q1, 0.f));
                hpA0.y = pkh(fmaxf(a0[2] + q2, 0.f), fmaxf(a0[3] + q3, 0.f));
                hpB0.x = pkh(fmaxf(a1[0] + q0, 0.f), fmaxf(a1[1] + q1, 0.f));
                hpB0.y = pkh(fmaxf(a1[2] + q2, 0.f), fmaxf(a1[3] + q3, 0.f));
            }
            {   // mt = 2k4 + 1
                const int mt = 2 * k4 + 1;
                uint2 qn = *reinterpret_cast<const uint2*>(
                    &Qnh[(size_t)node * DD + mt * 16 + g * 4]);
                half8 wf[4];
                #pragma unroll
                for (int kk = 0; kk < 4; ++kk)
                    wf[kk] = __builtin_bit_cast(half8, s_img[(mt * 4 + kk) * 64 + l]);
                f32x4 a0 = {0.f, 0.f, 0.f, 0.f}, a1 = {0.f, 0.f, 0.f, 0.f};
                #pragma unroll
                for (int kk = 0; kk < 4; ++kk)
                    a0 = __builtin_amdgcn_mfma_f32_16x16x32_f16(wf[kk], ub0[cur][kk], a0, 0, 0, 0);
                #pragma unroll
                for (int kk = 0; kk < 4; ++kk)
                    a1 = __builtin_amdgcn_mfma_f32_16x16x32_f16(wf[kk], ub1[cur][kk], a1, 0, 0, 0);
                float q0 = h2f_lo(qn.x), q1 = h2f_hi(qn.x);
                float q2 = h2f_lo(qn.y), q3 = h2f_hi(qn.y);
                hpA1.x = pkh(fmaxf(a0[0] + q0, 0.f), fmaxf(a0[1] + q1, 0.f));
                hpA1.y = pkh(fmaxf(a0[2] + q2, 0.f), fmaxf(a0[3] + q3, 0.f));
                hpB1.x = pkh(fmaxf(a1[0] + q0, 0.f), fmaxf(a1[1] + q1, 0.f));
                hpB1.y = pkh(fmaxf(a1[2] + q2, 0.f), fmaxf(a1[3] + q3, 0.f));
            }
            // relayout this k4; hp regs die here
            unsigned d[4], e[4];
            #pragma unroll
            for (int j = 0; j < 4; ++j) {
                int src = srcA + ((j >> 1) << 4);
                unsigned vE = (unsigned)__shfl((int)((j & 1) ? hpA0.y : hpA0.x), src);
                unsigned vO = (unsigned)__shfl((int)((j & 1) ? hpA1.y : hpA1.x), src);
                d[j] = hiSel ? vO : vE;
                unsigned uE = (unsigned)__shfl((int)((j & 1) ? hpB0.y : hpB0.x), src);
                unsigned uO = (unsigned)__shfl((int)((j & 1) ? hpB1.y : hpB1.x), src);
                e[j] = hiSel ? uO : uE;
            }
            uint4 du = {d[0], d[1], d[2], d[3]};
            uint4 eu = {e[0], e[1], e[2], e[3]};
            hb0[k4] = __builtin_bit_cast(half8, du);
            hb1[k4] = __builtin_bit_cast(half8, eu);
        }

        // ---- GEMM2 + logit fold (setprio: independent waves, attn-like)
        __builtin_amdgcn_s_setprio(1);
        float pl0 = 0.f, pl1 = 0.f;
        #pragma unroll
        for (int mt = 0; mt < 8; ++mt) {
            half8 wf[4];
            #pragma unroll
            for (int k4 = 0; k4 < 4; ++k4)
                wf[k4] = __builtin_bit_cast(half8, s_img[2048 + (mt * 4 + k4) * 64 + l]);
            float4 b2v = *reinterpret_cast<const float4*>(&b2[mt * 16 + g * 4]);
            float4 w3v = *reinterpret_cast<const float4*>(&w3[mt * 16 + g * 4]);
            f32x4 a0 = {0.f, 0.f, 0.f, 0.f}, a1 = {0.f, 0.f, 0.f, 0.f};
            #pragma unroll
            for (int k4 = 0; k4 < 4; ++k4)
                a0 = __builtin_amdgcn_mfma_f32_16x16x32_f16(wf[k4], hb0[k4], a0, 0, 0, 0);
            #pragma unroll
            for (int k4 = 0; k4 < 4; ++k4)
                a1 = __builtin_amdgcn_mfma_f32_16x16x32_f16(wf[k4], hb1[k4], a1, 0, 0, 0);
            pl0 += fmaxf(a0[0] + b2v.x, 0.f) * w3v.x + fmaxf(a0[1] + b2v.y, 0.f) * w3v.y
                 + fmaxf(a0[2] + b2v.z, 0.f) * w3v.z + fmaxf(a0[3] + b2v.w, 0.f) * w3v.w;
            pl1 += fmaxf(a1[0] + b2v.x, 0.f) * w3v.x + fmaxf(a1[1] + b2v.y, 0.f) * w3v.y
                 + fmaxf(a1[2] + b2v.z, 0.f) * w3v.z + fmaxf(a1[3] + b2v.w, 0.f) * w3v.w;
        }
        __builtin_amdgcn_s_setprio(0);
        pl0 += __shfl_xor(pl0, 16); pl0 += __shfl_xor(pl0, 32);
        pl1 += __shfl_xor(pl1, 16); pl1 += __shfl_xor(pl1, 32);

        // ---- in-wave softmax over the 32 edges
        float mx = fmaxf(pl0, pl1);
        #pragma unroll
        for (int mask = 1; mask <= 8; mask <<= 1) mx = fmaxf(mx, __shfl_xor(mx, mask));
        float e0 = __expf(pl0 - mx), e1 = __expf(pl1 - mx);
        float sm = e0 + e1;
        #pragma unroll
        for (int mask = 1; mask <= 8; mask <<= 1) sm += __shfl_xor(sm, mask);
        float inv = __frcp_rn(sm);
        float att0 = e0 * inv, att1 = e1 * inv;  // att for edges c and 16+c

        // ---- NOW issue next node's gathers (hb dead -> 32 regs free;
        // indices already resident). sched_barrier(0) pins placement.
        __builtin_amdgcn_sched_barrier(0);
        if (it < 4) {
            #pragma unroll
            for (int k4 = 0; k4 < 4; ++k4)
                ub0[nxt][k4] = *reinterpret_cast<const half8*>(
                    &ub16[(size_t)j0 * DD + k4 * 32 + koff]);
            #pragma unroll
            for (int k4 = 0; k4 < 4; ++k4)
                ub1[nxt][k4] = *reinterpret_cast<const half8*>(
                    &ub16[(size_t)j1 * DD + k4 * 32 + koff]);
        }

        // ---- weighted sum, ONE k4 at a time (8 live regs)
        #pragma unroll
        for (int k4 = 0; k4 < 4; ++k4) {
            float o8[8];
            #pragma unroll
            for (int i = 0; i < 8; ++i)
                o8[i] = att0 * (float)ub0[cur][k4][i] + att1 * (float)ub1[cur][k4][i];
            #pragma unroll
            for (int mask = 1; mask <= 8; mask <<= 1) {
                #pragma unroll
                for (int i = 0; i < 8; ++i)
                    o8[i] += __shfl_xor(o8[i], mask);
            }
            if (c == 0) {   // lanes (g,0): store ch = 32*k4 + 8*g + {0..7}
                float4 r0 = make_float4(o8[0], o8[1], o8[2], o8[3]);
                float4 r1 = make_float4(o8[4], o8[5], o8[6], o8[7]);
                out4[(size_t)node * 32 + k4 * 8 + g * 2]     = r0;
                out4[(size_t)node * 32 + k4 * 8 + g * 2 + 1] = r1;
            }
        }
    }
}

// ---------------------------------------------------------------------------
extern "C" void kernel_launch(void* const* d_in, const int* in_sizes, int n_in,
                              void* d_out, int out_size, void* d_ws, size_t ws_size,
                              hipStream_t stream)
{
    const int*   nodes = (const int*)  d_in[0];
    const int*   neigh = (const int*)  d_in[1];
    const float* u2e   = (const float*)d_in[3];
    const float* W1    = (const float*)d_in[4];
    const float* b1    = (const float*)d_in[5];
    const float* W2    = (const float*)d_in[6];
    const float* b2    = (const float*)d_in[7];
    const float* w3    = (const float*)d_in[8];
    // d_in[9] b3: cancels in segment softmax

    const int n = in_sizes[0];            // 20000
    const int U = in_sizes[3] / DD;       // 100000

    uint4*          w1img = (uint4*)d_ws;                    // 64 KB
    uint4*          w2t   = w1img + 4096;                    // 32 KB
    _Float16*       ub16  = (_Float16*)(w2t + 2048);         // 25.6 MB
    unsigned short* Qnh   = (unsigned short*)(ub16 + (size_t)U * DD); // 5.12 MB

    const int total8 = U * (DD / 8);      // 1.6M half8 chunks

    k_aux<<<24 + (total8 + 255) / 256, 256, 0, stream>>>(
        W1, W2, (const float4*)u2e, w1img, w2t, (uint4*)ub16, total8);
    k_qn<<<(n + 127) / 128, 256, 0, stream>>>(nodes, u2e, w1img, b1, Qnh, n);
    k_node<<<512, 512, 0, stream>>>(neigh, ub16, Qnh, w1img, w2t,
                                    b2, w3, (float4*)d_out, n);
}

// Round 20
// 97.660 us; speedup vs baseline: 1.0617x; 1.0319x over previous
//
#include <hip/hip_runtime.h>
#include <hip/hip_bf16.h>

#define DD 128
#define DEG 32

typedef __attribute__((ext_vector_type(8))) _Float16 half8;
typedef __attribute__((ext_vector_type(4))) float f32x4;

__device__ __forceinline__ unsigned pkh(float a, float b) {
    _Float16 ha = (_Float16)a, hb = (_Float16)b;     // RNE v_cvt_f16_f32
    return (unsigned)__builtin_bit_cast(unsigned short, ha)
         | ((unsigned)__builtin_bit_cast(unsigned short, hb) << 16);
}
__device__ __forceinline__ float h2f_lo(unsigned u) {
    return (float)__builtin_bit_cast(_Float16, (unsigned short)(u & 0xffff));
}
__device__ __forceinline__ float h2f_hi(unsigned u) {
    return (float)__builtin_bit_cast(_Float16, (unsigned short)(u >> 16));
}

// ---------------------------------------------------------------------------
// k_aux: fused prep (blocks 0..23) + cast (remaining blocks).
//  w1img[(nt*4+k4)*64+l][i] = B1[k4*32+(l>>4)*8+i][nt*16+(l&15)]  (fp16)
//     B1[k][n] = W1[k][n] (n<128 -> "W1a") | W1[128+k][n-128] (n>=128 -> "W1b")
//  w2t  [(mt*4+k4)*64+l][i] = W2[k4*32+(l>>4)*8+i][mt*16+(l&15)]  (fp16)
//  ub16 = fp16(u2e), streaming cast.
// ---------------------------------------------------------------------------
__global__ __launch_bounds__(256) void k_aux(
    const float* __restrict__ W1, const float* __restrict__ W2,
    const float4* __restrict__ u2e4, uint4* __restrict__ w1img,
    uint4* __restrict__ w2t, uint4* __restrict__ ub16v, int total8)
{
    const int bid = blockIdx.x;
    if (bid < 24) {
        int t = bid * 256 + threadIdx.x;
        if (t < 4096) {
            int l = t & 63, f = t >> 6, k4 = f & 3, nt = f >> 2;
            int n = nt * 16 + (l & 15), kb = k4 * 32 + ((l >> 4) & 3) * 8;
            float v[8];
            #pragma unroll
            for (int i = 0; i < 8; ++i) {
                int k = kb + i;
                v[i] = (n < DD) ? W1[k * DD + n] : W1[(DD + k) * DD + (n - DD)];
            }
            uint4 r;
            r.x = pkh(v[0], v[1]); r.y = pkh(v[2], v[3]);
            r.z = pkh(v[4], v[5]); r.w = pkh(v[6], v[7]);
            w1img[t] = r;
        } else if (t < 6144) {
            int q = t - 4096;
            int l = q & 63, f = q >> 6, k4 = f & 3, mt = f >> 2;
            int ch = mt * 16 + (l & 15), kb = k4 * 32 + ((l >> 4) & 3) * 8;
            float v[8];
            #pragma unroll
            for (int i = 0; i < 8; ++i) v[i] = W2[(kb + i) * DD + ch];
            uint4 r;
            r.x = pkh(v[0], v[1]); r.y = pkh(v[2], v[3]);
            r.z = pkh(v[4], v[5]); r.w = pkh(v[6], v[7]);
            w2t[q] = r;
        }
    } else {
        int i = (bid - 24) * 256 + threadIdx.x;
        if (i < total8) {
            float4 v0 = u2e4[(size_t)i * 2], v1 = u2e4[(size_t)i * 2 + 1];
            uint4 r;
            r.x = pkh(v0.x, v0.y); r.y = pkh(v0.z, v0.w);
            r.z = pkh(v1.x, v1.y); r.w = pkh(v1.z, v1.w);
            ub16v[i] = r;
        }
    }
}

// ---------------------------------------------------------------------------
// k_qn: Qnh[i] = fp16(u2e[nodes[i]] @ W1b + b1) — only the 20k centers.
// Per-lane gathered fp32->fp16 A-fragments, B=w1b image (w1img nt 8..15).
// ---------------------------------------------------------------------------
__global__ __launch_bounds__(256) void k_qn(
    const int* __restrict__ nodes, const float* __restrict__ u2e,
    const uint4* __restrict__ w1img, const float* __restrict__ b1,
    unsigned short* __restrict__ Qnh, int n)
{
    const int t = threadIdx.x, w = t >> 6, l = t & 63;
    const int base = blockIdx.x * 128;

    half8 a[2][4];
    #pragma unroll
    for (int nt = 0; nt < 2; ++nt) {
        int row = min(base + w * 32 + nt * 16 + (l & 15), n - 1);
        int user = nodes[row];
        const float* rp = u2e + (size_t)user * DD + ((l >> 4) << 3);
        #pragma unroll
        for (int k4 = 0; k4 < 4; ++k4) {
            float4 v0 = *reinterpret_cast<const float4*>(rp + k4 * 32);
            float4 v1 = *reinterpret_cast<const float4*>(rp + k4 * 32 + 4);
            uint4 r;
            r.x = pkh(v0.x, v0.y); r.y = pkh(v0.z, v0.w);
            r.z = pkh(v1.x, v1.y); r.w = pkh(v1.z, v1.w);
            a[nt][k4] = __builtin_bit_cast(half8, r);
        }
    }
    const int chq = (l >> 4) << 2;
    #pragma unroll
    for (int mt = 0; mt < 8; ++mt) {
        half8 wf[4];
        #pragma unroll
        for (int k4 = 0; k4 < 4; ++k4)
            wf[k4] = __builtin_bit_cast(half8, w1img[((8 + mt) * 4 + k4) * 64 + l]);
        float4 b1v = *reinterpret_cast<const float4*>(&b1[mt * 16 + chq]);
        #pragma unroll
        for (int nt = 0; nt < 2; ++nt) {
            f32x4 acc = {0.f, 0.f, 0.f, 0.f};
            #pragma unroll
            for (int k4 = 0; k4 < 4; ++k4)
                acc = __builtin_amdgcn_mfma_f32_16x16x32_f16(wf[k4], a[nt][k4], acc, 0, 0, 0);
            int row = base + w * 32 + nt * 16 + (l & 15);
            if (row < n) {
                uint2 pk;
                pk.x = pkh(acc[0] + b1v.x, acc[1] + b1v.y);
                pk.y = pkh(acc[2] + b1v.z, acc[3] + b1v.w);
                *reinterpret_cast<uint2*>(&Qnh[(size_t)row * DD + mt * 16 + chq]) = pk;
            }
        }
    }
}

// ---------------------------------------------------------------------------
// k_node: PERSISTENT — 512 blocks x 512 thr, 1 node/wave/iter, 5 nodes/wave.
// ROUND-17 EXACT (best measured: 82.4us steady, 97.7us total, ~1.7MB spill).
// Both weight images in LDS (64KB). Post-softmax gather placement: next
// node's ub gathers issue after GEMM2+softmax when hb (32 regs) is dead —
// the ONLY placement that fits the 128-reg/wave budget (unified VGPR+AGPR).
// Every variation tried (qnh ping-pong r18, index prefetch r19, ub ping-pong
// through GEMM2 r14/r15, 32KB LDS r16, 1024-thr r13) spilled or lost TLP.
// sched_barrier(0) pins the gather block below GEMM2.
// ---------------------------------------------------------------------------
__global__ __launch_bounds__(512, 4) void k_node(
    const int* __restrict__ neigh, const _Float16* __restrict__ ub16,
    const unsigned short* __restrict__ Qnh, const uint4* __restrict__ w1img,
    const uint4* __restrict__ w2t, const float* __restrict__ b2,
    const float* __restrict__ w3, float4* __restrict__ out4, int n)
{
    __shared__ uint4 s_img[4096];     // [0..2047]=w1a frags, [2048..4095]=w2t

    const int t = threadIdx.x, w = t >> 6, l = t & 63;
    const int g = l >> 4, c = l & 15;
    const int koff = g * 8;
    const int base = blockIdx.x * 40 + w * 5;   // this wave's 5 nodes

    // ---- prologue: issue it=0 gathers before staging (overlap)
    half8 ub0[2][4], ub1[2][4];
    {
        int node0 = min(base, n - 1);
        int i0 = neigh[node0 * DEG + c];
        int i1 = neigh[node0 * DEG + 16 + c];
        #pragma unroll
        for (int k4 = 0; k4 < 4; ++k4)
            ub0[0][k4] = *reinterpret_cast<const half8*>(
                &ub16[(size_t)i0 * DD + k4 * 32 + koff]);
        #pragma unroll
        for (int k4 = 0; k4 < 4; ++k4)
            ub1[0][k4] = *reinterpret_cast<const half8*>(
                &ub16[(size_t)i1 * DD + k4 * 32 + koff]);
    }

    // ---- stage weight images once
    #pragma unroll
    for (int i = 0; i < 4; ++i) s_img[i * 512 + t] = w1img[i * 512 + t];
    #pragma unroll
    for (int i = 0; i < 4; ++i) s_img[2048 + i * 512 + t] = w2t[i * 512 + t];
    __syncthreads();

    const int srcA = ((g & 1) << 5) + c;
    const int hiSel = g >> 1;

    #pragma unroll
    for (int it = 0; it < 5; ++it) {
        const int cur = it & 1, nxt = cur ^ 1;
        const int node = min(base + it, n - 1);

        // ---- fused GEMM1 + epilogue + relayout, one k4 (2 ch-tiles) at a time
        half8 hb0[4], hb1[4];
        #pragma unroll
        for (int k4 = 0; k4 < 4; ++k4) {
            uint2 hpA0, hpA1, hpB0, hpB1;   // hp{edge-half}{mt-parity}
            {   // mt = 2k4
                const int mt = 2 * k4;
                uint2 qn = *reinterpret_cast<const uint2*>(
                    &Qnh[(size_t)node * DD + mt * 16 + g * 4]);
                half8 wf[4];
                #pragma unroll
                for (int kk = 0; kk < 4; ++kk)
                    wf[kk] = __builtin_bit_cast(half8, s_img[(mt * 4 + kk) * 64 + l]);
                f32x4 a0 = {0.f, 0.f, 0.f, 0.f}, a1 = {0.f, 0.f, 0.f, 0.f};
                #pragma unroll
                for (int kk = 0; kk < 4; ++kk)
                    a0 = __builtin_amdgcn_mfma_f32_16x16x32_f16(wf[kk], ub0[cur][kk], a0, 0, 0, 0);
                #pragma unroll
                for (int kk = 0; kk < 4; ++kk)
                    a1 = __builtin_amdgcn_mfma_f32_16x16x32_f16(wf[kk], ub1[cur][kk], a1, 0, 0, 0);
                float q0 = h2f_lo(qn.x), q1 = h2f_hi(qn.x);
                float q2 = h2f_lo(qn.y), q3 = h2f_hi(qn.y);
                hpA0.x = pkh(fmaxf(a0[0] + q0, 0.f), fmaxf(a0[1] + q1, 0.f));
                hpA0.y = pkh(fmaxf(a0[2] + q2, 0.f), fmaxf(a0[3] + q3, 0.f));
                hpB0.x = pkh(fmaxf(a1[0] + q0, 0.f), fmaxf(a1[1] + q1, 0.f));
                hpB0.y = pkh(fmaxf(a1[2] + q2, 0.f), fmaxf(a1[3] + q3, 0.f));
            }
            {   // mt = 2k4 + 1
                const int mt = 2 * k4 + 1;
                uint2 qn = *reinterpret_cast<const uint2*>(
                    &Qnh[(size_t)node * DD + mt * 16 + g * 4]);
                half8 wf[4];
                #pragma unroll
                for (int kk = 0; kk < 4; ++kk)
                    wf[kk] = __builtin_bit_cast(half8, s_img[(mt * 4 + kk) * 64 + l]);
                f32x4 a0 = {0.f, 0.f, 0.f, 0.f}, a1 = {0.f, 0.f, 0.f, 0.f};
                #pragma unroll
                for (int kk = 0; kk < 4; ++kk)
                    a0 = __builtin_amdgcn_mfma_f32_16x16x32_f16(wf[kk], ub0[cur][kk], a0, 0, 0, 0);
                #pragma unroll
                for (int kk = 0; kk < 4; ++kk)
                    a1 = __builtin_amdgcn_mfma_f32_16x16x32_f16(wf[kk], ub1[cur][kk], a1, 0, 0, 0);
                float q0 = h2f_lo(qn.x), q1 = h2f_hi(qn.x);
                float q2 = h2f_lo(qn.y), q3 = h2f_hi(qn.y);
                hpA1.x = pkh(fmaxf(a0[0] + q0, 0.f), fmaxf(a0[1] + q1, 0.f));
                hpA1.y = pkh(fmaxf(a0[2] + q2, 0.f), fmaxf(a0[3] + q3, 0.f));
                hpB1.x = pkh(fmaxf(a1[0] + q0, 0.f), fmaxf(a1[1] + q1, 0.f));
                hpB1.y = pkh(fmaxf(a1[2] + q2, 0.f), fmaxf(a1[3] + q3, 0.f));
            }
            // relayout this k4; hp regs die here
            unsigned d[4], e[4];
            #pragma unroll
            for (int j = 0; j < 4; ++j) {
                int src = srcA + ((j >> 1) << 4);
                unsigned vE = (unsigned)__shfl((int)((j & 1) ? hpA0.y : hpA0.x), src);
                unsigned vO = (unsigned)__shfl((int)((j & 1) ? hpA1.y : hpA1.x), src);
                d[j] = hiSel ? vO : vE;
                unsigned uE = (unsigned)__shfl((int)((j & 1) ? hpB0.y : hpB0.x), src);
                unsigned uO = (unsigned)__shfl((int)((j & 1) ? hpB1.y : hpB1.x), src);
                e[j] = hiSel ? uO : uE;
            }
            uint4 du = {d[0], d[1], d[2], d[3]};
            uint4 eu = {e[0], e[1], e[2], e[3]};
            hb0[k4] = __builtin_bit_cast(half8, du);
            hb1[k4] = __builtin_bit_cast(half8, eu);
        }

        // ---- GEMM2 + logit fold (setprio: independent waves, attn-like)
        __builtin_amdgcn_s_setprio(1);
        float pl0 = 0.f, pl1 = 0.f;
        #pragma unroll
        for (int mt = 0; mt < 8; ++mt) {
            half8 wf[4];
            #pragma unroll
            for (int k4 = 0; k4 < 4; ++k4)
                wf[k4] = __builtin_bit_cast(half8, s_img[2048 + (mt * 4 + k4) * 64 + l]);
            float4 b2v = *reinterpret_cast<const float4*>(&b2[mt * 16 + g * 4]);
            float4 w3v = *reinterpret_cast<const float4*>(&w3[mt * 16 + g * 4]);
            f32x4 a0 = {0.f, 0.f, 0.f, 0.f}, a1 = {0.f, 0.f, 0.f, 0.f};
            #pragma unroll
            for (int k4 = 0; k4 < 4; ++k4)
                a0 = __builtin_amdgcn_mfma_f32_16x16x32_f16(wf[k4], hb0[k4], a0, 0, 0, 0);
            #pragma unroll
            for (int k4 = 0; k4 < 4; ++k4)
                a1 = __builtin_amdgcn_mfma_f32_16x16x32_f16(wf[k4], hb1[k4], a1, 0, 0, 0);
            pl0 += fmaxf(a0[0] + b2v.x, 0.f) * w3v.x + fmaxf(a0[1] + b2v.y, 0.f) * w3v.y
                 + fmaxf(a0[2] + b2v.z, 0.f) * w3v.z + fmaxf(a0[3] + b2v.w, 0.f) * w3v.w;
            pl1 += fmaxf(a1[0] + b2v.x, 0.f) * w3v.x + fmaxf(a1[1] + b2v.y, 0.f) * w3v.y
                 + fmaxf(a1[2] + b2v.z, 0.f) * w3v.z + fmaxf(a1[3] + b2v.w, 0.f) * w3v.w;
        }
        __builtin_amdgcn_s_setprio(0);
        pl0 += __shfl_xor(pl0, 16); pl0 += __shfl_xor(pl0, 32);
        pl1 += __shfl_xor(pl1, 16); pl1 += __shfl_xor(pl1, 32);

        // ---- in-wave softmax over the 32 edges
        float mx = fmaxf(pl0, pl1);
        #pragma unroll
        for (int mask = 1; mask <= 8; mask <<= 1) mx = fmaxf(mx, __shfl_xor(mx, mask));
        float e0 = __expf(pl0 - mx), e1 = __expf(pl1 - mx);
        float sm = e0 + e1;
        #pragma unroll
        for (int mask = 1; mask <= 8; mask <<= 1) sm += __shfl_xor(sm, mask);
        float inv = __frcp_rn(sm);
        float att0 = e0 * inv, att1 = e1 * inv;  // att for edges c and 16+c

        // ---- NOW issue next node's gathers (hb dead -> 32 regs free).
        // sched_barrier(0) pins placement (must not hoist into GEMM2).
        __builtin_amdgcn_sched_barrier(0);
        if (it < 4) {
            int nn = min(base + it + 1, n - 1);
            int j0 = neigh[nn * DEG + c];
            int j1 = neigh[nn * DEG + 16 + c];
            #pragma unroll
            for (int k4 = 0; k4 < 4; ++k4)
                ub0[nxt][k4] = *reinterpret_cast<const half8*>(
                    &ub16[(size_t)j0 * DD + k4 * 32 + koff]);
            #pragma unroll
            for (int k4 = 0; k4 < 4; ++k4)
                ub1[nxt][k4] = *reinterpret_cast<const half8*>(
                    &ub16[(size_t)j1 * DD + k4 * 32 + koff]);
        }

        // ---- weighted sum, ONE k4 at a time (8 live regs)
        #pragma unroll
        for (int k4 = 0; k4 < 4; ++k4) {
            float o8[8];
            #pragma unroll
            for (int i = 0; i < 8; ++i)
                o8[i] = att0 * (float)ub0[cur][k4][i] + att1 * (float)ub1[cur][k4][i];
            #pragma unroll
            for (int mask = 1; mask <= 8; mask <<= 1) {
                #pragma unroll
                for (int i = 0; i < 8; ++i)
                    o8[i] += __shfl_xor(o8[i], mask);
            }
            if (c == 0) {   // lanes (g,0): store ch = 32*k4 + 8*g + {0..7}
                float4 r0 = make_float4(o8[0], o8[1], o8[2], o8[3]);
                float4 r1 = make_float4(o8[4], o8[5], o8[6], o8[7]);
                out4[(size_t)node * 32 + k4 * 8 + g * 2]     = r0;
                out4[(size_t)node * 32 + k4 * 8 + g * 2 + 1] = r1;
            }
        }
    }
}

// ---------------------------------------------------------------------------
extern "C" void kernel_launch(void* const* d_in, const int* in_sizes, int n_in,
                              void* d_out, int out_size, void* d_ws, size_t ws_size,
                              hipStream_t stream)
{
    const int*   nodes = (const int*)  d_in[0];
    const int*   neigh = (const int*)  d_in[1];
    const float* u2e   = (const float*)d_in[3];
    const float* W1    = (const float*)d_in[4];
    const float* b1    = (const float*)d_in[5];
    const float* W2    = (const float*)d_in[6];
    const float* b2    = (const float*)d_in[7];
    const float* w3    = (const float*)d_in[8];
    // d_in[9] b3: cancels in segment softmax

    const int n = in_sizes[0];            // 20000
    const int U = in_sizes[3] / DD;       // 100000

    uint4*          w1img = (uint4*)d_ws;                    // 64 KB
    uint4*          w2t   = w1img + 4096;                    // 32 KB
    _Float16*       ub16  = (_Float16*)(w2t + 2048);         // 25.6 MB
    unsigned short* Qnh   = (unsigned short*)(ub16 + (size_t)U * DD); // 5.12 MB

    const int total8 = U * (DD / 8);      // 1.6M half8 chunks

    k_aux<<<24 + (total8 + 255) / 256, 256, 0, stream>>>(
        W1, W2, (const float4*)u2e, w1img, w2t, (uint4*)ub16, total8);
    k_qn<<<(n + 127) / 128, 256, 0, stream>>>(nodes, u2e, w1img, b1, Qnh, n);
    k_node<<<512, 512, 0, stream>>>(neigh, ub16, Qnh, w1img, w2t,
                                    b2, w3, (float4*)d_out, n);
}